// Round 8
// baseline (248.164 us; speedup 1.0000x reference)
//
#include <hip/hip_runtime.h>

// FFNN Transducer fused forward — R8.
// Joint & enc: single-barrier double-buffered LDS pipeline (was 2 barriers/chunk).
// Pred: 8 rows/block, wave=(4rows x 128cols), lane=2cols, prefetched float2
//       weights -> FMA-bound (was LDS-broadcast + latency bound).
// Numerics: fp16 2-term A split x single-RNE-fp16 B (unchanged from R7).
// Inputs (setup_inputs order):
//  0 encoder_states (8,512,512) f32     1 encoder_states_size (8) i32
//  2 targets (8,64) i32                 3 targets_size (8) i32
//  4 emb (128,128) f32                  5 W1 (256,256)  6 b1 (256)
//  7 W2 (256,256)  8 b2 (256)           9 Wj1 (768,512) 10 bj1 (512)
// 11 Wj2 (512,128) 12 bj2 (128)
// Output: (8,512,65,128) f32, masked.

#define VOCAB 128
#define EMBD  128
#define ENCD  512
#define PREDD 256
#define JOIND 512
#define NB    8
#define NT    512
#define NUT   64
#define UP1   65

typedef __fp16   pk16x2 __attribute__((ext_vector_type(2)));   // cvt_pkrtz ret
typedef _Float16 f16x8  __attribute__((ext_vector_type(8)));
typedef float    f32x4  __attribute__((ext_vector_type(4)));

__device__ __forceinline__ float frelu(float x) { return x > 0.f ? x : 0.f; }

// Split two f32 into packed fp16 hi (RTZ) + fp16 lo (RTZ of residual).
__device__ __forceinline__ void splitf16_2(float x0, float x1,
                                           unsigned& hi, unsigned& lo) {
    pk16x2 h = __builtin_amdgcn_cvt_pkrtz(x0, x1);
    float r0 = x0 - (float)h.x;
    float r1 = x1 - (float)h.y;
    pk16x2 l = __builtin_amdgcn_cvt_pkrtz(r0, r1);
    __builtin_memcpy(&hi, &h, 4);
    __builtin_memcpy(&lo, &l, 4);
}

// ---------------------------------------------------------------------------
// Prep: swizzled single-fp16 B-images for joint (Wj2^T) and enc (We^T).
// Per 32-k chunk: row n holds 4 16B slots (8 f16); physical slot p stores
// k-slot (p ^ (n&3)). Consumers stage with a linear aligned copy.
// ---------------------------------------------------------------------------
__global__ __launch_bounds__(256) void prep_weights(
    const float* __restrict__ Wj2, const float* __restrict__ Wj1,
    unsigned short* __restrict__ WjF, unsigned short* __restrict__ WeF)
{
    const int idx = blockIdx.x * 256 + threadIdx.x;   // 0..327679
    float x; unsigned short* dst;
    if (idx < VOCAB * JOIND) {
        const int c = idx >> 12, rem = idx & 4095;
        const int n = rem >> 5, p = (rem >> 3) & 3, e = rem & 7;
        const int k = c * 32 + ((p ^ (n & 3)) << 3) + e;
        x = Wj2[k * VOCAB + n];
        dst = WjF + idx;
    } else {
        const int j = idx - VOCAB * JOIND;            // 0..262143
        const int ct = j >> 16, rem1 = j & 65535;
        const int c = rem1 >> 12, rem = rem1 & 4095;
        const int nl = rem >> 5, p = (rem >> 3) & 3, e = rem & 7;
        const int n = ct * 128 + nl;
        const int k = c * 32 + ((p ^ (nl & 3)) << 3) + e;
        x = Wj1[(size_t)k * JOIND + n];
        dst = WeF + j;
    }
    const _Float16 h = (_Float16)x;                   // RNE
    unsigned short bits; __builtin_memcpy(&bits, &h, 2);
    *dst = bits;
}

// ---------------------------------------------------------------------------
// Pred hidden layer: out[8][256] = relu(in[8][256] @ W[256][256] + b).
// Wave (rg = 4-row group, 128-col half); lane owns 2 cols. Weights prefetched.
// ---------------------------------------------------------------------------
__device__ __forceinline__ void pred_layer(
    const float (*in)[256], const float* __restrict__ W,
    const float* __restrict__ bias, float (*out)[256], int rg, int c2)
{
    float f[4][2] = {};
    float2 w[8], wn[8];
    #pragma unroll
    for (int j = 0; j < 8; ++j) w[j] = *(const float2*)&W[j * PREDD + c2];
    for (int kb = 0; kb < 32; ++kb) {
        const int k = kb * 8;
        if (kb < 31) {
            #pragma unroll
            for (int j = 0; j < 8; ++j)
                wn[j] = *(const float2*)&W[(k + 8 + j) * PREDD + c2];
        }
        #pragma unroll
        for (int half = 0; half < 2; ++half) {
            f32x4 iv[4];
            #pragma unroll
            for (int r = 0; r < 4; ++r)
                iv[r] = *(const f32x4*)&in[rg + r][k + half * 4];
            #pragma unroll
            for (int jj = 0; jj < 4; ++jj) {
                const int j = half * 4 + jj;
                #pragma unroll
                for (int r = 0; r < 4; ++r) {
                    f[r][0] = fmaf(iv[r][jj], w[j].x, f[r][0]);
                    f[r][1] = fmaf(iv[r][jj], w[j].y, f[r][1]);
                }
            }
        }
        if (kb < 31) {
            #pragma unroll
            for (int j = 0; j < 8; ++j) w[j] = wn[j];
        }
    }
    const float2 bb = *(const float2*)&bias[c2];
    #pragma unroll
    for (int r = 0; r < 4; ++r) {
        float2 o = {frelu(f[r][0] + bb.x), frelu(f[r][1] + bb.y)};
        *(float2*)&out[rg + r][c2] = o;
    }
}

// ---------------------------------------------------------------------------
// Fused pred-net + enc_proj: bx<65 -> pred (8 rows each), else enc tile.
// ---------------------------------------------------------------------------
__global__ __launch_bounds__(256, 3) void fused_pe(
    const int* __restrict__ targets, const int* __restrict__ tsz,
    const float* __restrict__ emb,
    const float* __restrict__ W1, const float* __restrict__ b1,
    const float* __restrict__ W2, const float* __restrict__ b2,
    const float* __restrict__ Wj1, const float* __restrict__ bj1,
    float* __restrict__ pproj,
    const float* __restrict__ A,
    const unsigned short* __restrict__ WeF,
    const int* __restrict__ esz, float* __restrict__ eproj)
{
    __shared__ __align__(16) unsigned char smem[49152];
    const int tid = threadIdx.x;

    if (blockIdx.x < 65) {
        // ================= pred part =================
        float (*eS)[256] = (float(*)[256])smem;           // 8KB
        float (*pS)[256] = (float(*)[256])(smem + 8192);  // 8KB
        const int r0 = blockIdx.x * 8;

        bool anyLive = false;
        #pragma unroll
        for (int i = 0; i < 8; ++i) {
            const int row = r0 + i, b = row / UP1, u = row - b * UP1;
            anyLive = anyLive || (u <= tsz[b]);
        }
        if (!anyLive) return;

        #pragma unroll
        for (int i = 0; i < 8; ++i) {
            const int row = r0 + i, b = row / UP1, u = row - b * UP1;
            const int c0 = (u >= 1) ? targets[b * NUT + u - 1] : (VOCAB - 1);
            const int c1 = (u >= 2) ? targets[b * NUT + u - 2] : (VOCAB - 1);
            eS[i][tid] = (tid < EMBD) ? emb[c0 * EMBD + tid]
                                      : emb[c1 * EMBD + (tid - EMBD)];
        }
        __syncthreads();

        const int wv = tid >> 6, lane = tid & 63;
        const int rg = (wv & 1) * 4;
        const int c2 = (wv >> 1) * 128 + lane * 2;

        pred_layer(eS, W1, b1, pS, rg, c2);   // layer 1
        __syncthreads();
        pred_layer(pS, W2, b2, eS, rg, c2);   // layer 2 (q -> eS)
        __syncthreads();

        // projection: pproj rows = q @ Wp + bj1 (512 cols; lane owns 4)
        const int c4 = (wv >> 1) * 256 + lane * 4;
        float g[4][4] = {};
        f32x4 w4[8], wn4[8];
        #pragma unroll
        for (int j = 0; j < 8; ++j)
            w4[j] = *(const f32x4*)&Wj1[(size_t)(ENCD + j) * JOIND + c4];
        for (int kb = 0; kb < 32; ++kb) {
            const int k = kb * 8;
            if (kb < 31) {
                #pragma unroll
                for (int j = 0; j < 8; ++j)
                    wn4[j] = *(const f32x4*)&Wj1[(size_t)(ENCD + k + 8 + j) * JOIND + c4];
            }
            #pragma unroll
            for (int half = 0; half < 2; ++half) {
                f32x4 iv[4];
                #pragma unroll
                for (int r = 0; r < 4; ++r)
                    iv[r] = *(const f32x4*)&eS[rg + r][k + half * 4];
                #pragma unroll
                for (int jj = 0; jj < 4; ++jj) {
                    const int j = half * 4 + jj;
                    #pragma unroll
                    for (int r = 0; r < 4; ++r)
                        #pragma unroll
                        for (int cc = 0; cc < 4; ++cc)
                            g[r][cc] = fmaf(iv[r][jj], w4[j][cc], g[r][cc]);
                }
            }
            if (kb < 31) {
                #pragma unroll
                for (int j = 0; j < 8; ++j) w4[j] = wn4[j];
            }
        }
        const f32x4 bb4 = *(const f32x4*)&bj1[c4];
        #pragma unroll
        for (int r = 0; r < 4; ++r) {
            f32x4 o;
            #pragma unroll
            for (int cc = 0; cc < 4; ++cc) o[cc] = g[r][cc] + bb4[cc];
            *(f32x4*)&pproj[(size_t)(r0 + rg + r) * JOIND + c4] = o;
        }
        return;
    }

    // ================= enc part (dbuf, single barrier/chunk) =================
    unsigned short (*AhS)[4096] = (unsigned short(*)[4096])smem;             // 16KB
    unsigned short (*AlS)[4096] = (unsigned short(*)[4096])(smem + 16384);   // 16KB
    unsigned short (*BhS)[4096] = (unsigned short(*)[4096])(smem + 32768);   // 16KB

    const int bxe = blockIdx.x - 65;
    const int rTile = bxe >> 2;                   // 0..31
    const int ct = bxe & 3;
    const int b = rTile >> 2;
    const int t0 = (rTile & 3) * 128;
    if (t0 >= esz[b]) return;

    const int q = tid & 7;
    const float* ap[4]; int offA[4];
    #pragma unroll
    for (int p = 0; p < 4; ++p) {
        const int r = p * 32 + (tid >> 3);
        ap[p] = A + (size_t)(rTile * 128 + r) * ENCD + q * 4;
        offA[p] = r * 32 + (((q >> 1) ^ (r & 3)) << 3) + ((q & 1) << 2);
    }
    const size_t wbase = (size_t)ct * 65536;      // f16 units

    const int lane = tid & 63, w = tid >> 6;
    const int wr = w >> 1, wc = w & 1;
    const int l15 = lane & 15, lj = lane >> 4;
    const int sw = lj ^ (l15 & 3);

    f32x4 acc[4][4];
    #pragma unroll
    for (int mt = 0; mt < 4; ++mt)
        #pragma unroll
        for (int nt = 0; nt < 4; ++nt)
            acc[mt][nt] = (f32x4){0.f, 0.f, 0.f, 0.f};

    float4 aReg[4]; uint4 bReg0, bReg1;
    // prologue: load + store chunk 0 into buf 0
    #pragma unroll
    for (int p = 0; p < 4; ++p) aReg[p] = *(const float4*)(ap[p]);
    bReg0 = *(const uint4*)&WeF[wbase + (size_t)tid * 8];
    bReg1 = *(const uint4*)&WeF[wbase + (size_t)(tid + 256) * 8];
    #pragma unroll
    for (int p = 0; p < 4; ++p) {
        unsigned h0, h1, l0, l1;
        splitf16_2(aReg[p].x, aReg[p].y, h0, l0);
        splitf16_2(aReg[p].z, aReg[p].w, h1, l1);
        *(uint2*)&AhS[0][offA[p]] = make_uint2(h0, h1);
        *(uint2*)&AlS[0][offA[p]] = make_uint2(l0, l1);
    }
    *(uint4*)&BhS[0][tid * 8] = bReg0;
    *(uint4*)&BhS[0][(tid + 256) * 8] = bReg1;
    __syncthreads();

    for (int c = 0; c < 16; ++c) {
        const int cur = c & 1, nxt = cur ^ 1;
        if (c < 15) {   // issue next-chunk loads
            const int kc = (c + 1) * 32;
            #pragma unroll
            for (int p = 0; p < 4; ++p) aReg[p] = *(const float4*)(ap[p] + kc);
            const size_t g = wbase + ((size_t)(c + 1) << 12);
            bReg0 = *(const uint4*)&WeF[g + (size_t)tid * 8];
            bReg1 = *(const uint4*)&WeF[g + (size_t)(tid + 256) * 8];
        }
        // compute chunk c from buf cur
        f16x8 bh[4];
        #pragma unroll
        for (int nt = 0; nt < 4; ++nt) {
            const int n = wc * 64 + nt * 16 + l15;
            bh[nt] = *(const f16x8*)&BhS[cur][n * 32 + (sw << 3)];
        }
        #pragma unroll
        for (int mt = 0; mt < 4; ++mt) {
            const int m = wr * 64 + mt * 16 + l15;
            const int off = m * 32 + (sw << 3);
            const f16x8 ah = *(const f16x8*)&AhS[cur][off];
            const f16x8 al = *(const f16x8*)&AlS[cur][off];
            #pragma unroll
            for (int nt = 0; nt < 4; ++nt) {
                acc[mt][nt] = __builtin_amdgcn_mfma_f32_16x16x32_f16(ah, bh[nt], acc[mt][nt], 0, 0, 0);
                acc[mt][nt] = __builtin_amdgcn_mfma_f32_16x16x32_f16(al, bh[nt], acc[mt][nt], 0, 0, 0);
            }
        }
        if (c < 15) {   // store next chunk into buf nxt
            #pragma unroll
            for (int p = 0; p < 4; ++p) {
                unsigned h0, h1, l0, l1;
                splitf16_2(aReg[p].x, aReg[p].y, h0, l0);
                splitf16_2(aReg[p].z, aReg[p].w, h1, l1);
                *(uint2*)&AhS[nxt][offA[p]] = make_uint2(h0, h1);
                *(uint2*)&AlS[nxt][offA[p]] = make_uint2(l0, l1);
            }
            *(uint4*)&BhS[nxt][tid * 8] = bReg0;
            *(uint4*)&BhS[nxt][(tid + 256) * 8] = bReg1;
        }
        __syncthreads();
    }
    #pragma unroll
    for (int mt = 0; mt < 4; ++mt)
        #pragma unroll
        for (int r4 = 0; r4 < 4; ++r4) {
            const int row = wr * 64 + mt * 16 + lj * 4 + r4;
            float* dst = eproj + (size_t)(rTile * 128 + row) * JOIND
                       + ct * 128 + wc * 64 + l15;
            #pragma unroll
            for (int nt = 0; nt < 4; ++nt) dst[nt * 16] = acc[mt][nt][r4];
        }
}

// ---------------------------------------------------------------------------
// Joint: 1-D grid 2304, XCD remap (one batch per XCD).
// Block = 128 rows (16t x 8u) x 128 v; 4 waves (2x2) of 64x64.
// Double-buffered LDS, ONE barrier per chunk. h built in-register (fp16 pair).
// ---------------------------------------------------------------------------
__global__ __launch_bounds__(256, 3) void joint_kernel(
    const float* __restrict__ Eproj, const float* __restrict__ Pproj,
    const unsigned short* __restrict__ WjF,
    const float* __restrict__ bj2,
    const int* __restrict__ esz, const int* __restrict__ tsz,
    float* __restrict__ out)
{
    const int flat = blockIdx.x;                      // 0..2303
    const int logical = (flat & 7) * 288 + (flat >> 3);
    const int b  = logical / 288;
    const int rem = logical - b * 288;
    const int t0 = (rem / 9) * 16;
    const int u0 = (rem % 9) * 8;
    const int tid = threadIdx.x;
    const int es = esz[b], ts = tsz[b];
    const int nu = (UP1 - u0 < 8) ? (UP1 - u0) : 8;   // 8 or 1

    if (t0 >= es || u0 > ts) {   // fully masked -> zero fill
        const float4 z = {0.f, 0.f, 0.f, 0.f};
        const int total = 16 * nu * 32;               // float4 count
        for (int idx = tid; idx < total; idx += 256) {
            const int slot = idx & 31;
            const int rr = idx >> 5;
            const int tt = (nu == 8) ? (rr >> 3) : rr;
            const int uu = (nu == 8) ? (rr & 7) : 0;
            *(float4*)&out[(((size_t)(b * NT + t0 + tt) * UP1 + (u0 + uu)) << 7) + slot * 4] = z;
        }
        return;
    }

    __shared__ __align__(16) unsigned short BhS[2][128 * 32];  // 2x8KB fp16
    __shared__ __align__(16) float eS[2][16 * 32];             // 2x2KB
    __shared__ __align__(16) float pS[2][8 * 32];              // 2x1KB

    // staging assignments
    const int erow = tid >> 3, es8 = tid & 7;               // tid < 128
    const float* egp = Eproj + ((size_t)(b * NT + t0 + (erow & 15))) * JOIND + es8 * 4;
    const int elpo = (erow & 15) * 32 + ((es8 ^ (erow & 7)) << 2);
    const int prow = (tid >> 3) & 7, ps8 = tid & 7;         // tid in [128,192)
    int pu = u0 + prow; if (pu > NUT) pu = NUT;
    const float* pgp = Pproj + ((size_t)(b * UP1 + pu)) * JOIND + ps8 * 4;
    const int plpo = prow * 32 + ((ps8 ^ (prow & 7)) << 2);

    const int lane = tid & 63, w = tid >> 6;
    const int wr = w >> 1, wc = w & 1;
    const int l15 = lane & 15, lj = lane >> 4;
    const int sw = lj ^ (l15 & 3);
    const int urow = l15 & 7;
    const int po = urow * 32 + (((lj << 1) ^ (urow & 7)) << 2);
    int eo[4];
    #pragma unroll
    for (int mt = 0; mt < 4; ++mt) {
        const int trow = wr * 8 + mt * 2 + (l15 >> 3);
        eo[mt] = trow * 32 + (((lj << 1) ^ (trow & 7)) << 2);
    }
    int bo[4];
    #pragma unroll
    for (int nt = 0; nt < 4; ++nt)
        bo[nt] = (wc * 64 + nt * 16 + l15) * 32 + (sw << 3);

    f32x4 acc[4][4];
    #pragma unroll
    for (int mt = 0; mt < 4; ++mt)
        #pragma unroll
        for (int nt = 0; nt < 4; ++nt)
            acc[mt][nt] = (f32x4){0.f, 0.f, 0.f, 0.f};

    float4 aReg; uint4 bReg0, bReg1;
    // prologue: load + store chunk 0 into buf 0
    if (tid < 128)       aReg = *(const float4*)egp;
    else if (tid < 192)  aReg = *(const float4*)pgp;
    bReg0 = *(const uint4*)&WjF[(size_t)tid * 8];
    bReg1 = *(const uint4*)&WjF[(size_t)(tid + 256) * 8];
    if (tid < 128)      *(float4*)&eS[0][elpo] = aReg;
    else if (tid < 192) *(float4*)&pS[0][plpo] = aReg;
    *(uint4*)&BhS[0][tid * 8] = bReg0;
    *(uint4*)&BhS[0][(tid + 256) * 8] = bReg1;
    __syncthreads();

    for (int c = 0; c < 16; ++c) {
        const int cur = c & 1, nxt = cur ^ 1;
        if (c < 15) {   // issue next-chunk loads
            const int kc = (c + 1) * 32;
            if (tid < 128)      aReg = *(const float4*)(egp + kc);
            else if (tid < 192) aReg = *(const float4*)(pgp + kc);
            const size_t g = (size_t)(c + 1) << 12;
            bReg0 = *(const uint4*)&WjF[g + (size_t)tid * 8];
            bReg1 = *(const uint4*)&WjF[g + (size_t)(tid + 256) * 8];
        }
        // compute chunk c from buf cur
        f16x8 bh[4];
        #pragma unroll
        for (int nt = 0; nt < 4; ++nt)
            bh[nt] = *(const f16x8*)&BhS[cur][bo[nt]];
        const float4 pf0 = *(const float4*)&pS[cur][po];
        const float4 pf1 = *(const float4*)&pS[cur][po ^ 4];
        #pragma unroll
        for (int mt = 0; mt < 4; ++mt) {
            const float4 ef0 = *(const float4*)&eS[cur][eo[mt]];
            const float4 ef1 = *(const float4*)&eS[cur][eo[mt] ^ 4];
            const float x0 = frelu(ef0.x + pf0.x), x1 = frelu(ef0.y + pf0.y);
            const float x2 = frelu(ef0.z + pf0.z), x3 = frelu(ef0.w + pf0.w);
            const float x4 = frelu(ef1.x + pf1.x), x5 = frelu(ef1.y + pf1.y);
            const float x6 = frelu(ef1.z + pf1.z), x7 = frelu(ef1.w + pf1.w);
            unsigned h0, h1, h2, h3, l0, l1, l2, l3;
            splitf16_2(x0, x1, h0, l0); splitf16_2(x2, x3, h1, l1);
            splitf16_2(x4, x5, h2, l2); splitf16_2(x6, x7, h3, l3);
            uint4 ahv = make_uint4(h0, h1, h2, h3);
            uint4 alv = make_uint4(l0, l1, l2, l3);
            const f16x8 ah = *(const f16x8*)&ahv;
            const f16x8 al = *(const f16x8*)&alv;
            #pragma unroll
            for (int nt = 0; nt < 4; ++nt) {
                acc[mt][nt] = __builtin_amdgcn_mfma_f32_16x16x32_f16(ah, bh[nt], acc[mt][nt], 0, 0, 0);
                acc[mt][nt] = __builtin_amdgcn_mfma_f32_16x16x32_f16(al, bh[nt], acc[mt][nt], 0, 0, 0);
            }
        }
        if (c < 15) {   // store next chunk into buf nxt
            if (tid < 128)      *(float4*)&eS[nxt][elpo] = aReg;
            else if (tid < 192) *(float4*)&pS[nxt][plpo] = aReg;
            *(uint4*)&BhS[nxt][tid * 8] = bReg0;
            *(uint4*)&BhS[nxt][(tid + 256) * 8] = bReg1;
        }
        __syncthreads();
    }

    // epilogue: +bj2, mask, store (D layout: col=lane&15, row=lj*4+reg)
    float bj[4];
    #pragma unroll
    for (int nt = 0; nt < 4; ++nt) bj[nt] = bj2[wc * 64 + nt * 16 + l15];

    #pragma unroll
    for (int mt = 0; mt < 4; ++mt) {
        #pragma unroll
        for (int r4 = 0; r4 < 4; ++r4) {
            const int row = wr * 64 + mt * 16 + lj * 4 + r4;
            const int t = t0 + (row >> 3);
            const int u = u0 + (row & 7);
            if (u >= UP1) continue;                  // u0=64 tiles only
            const bool valid = (t < es) && (u <= ts);
            float* __restrict__ orow =
                out + ((size_t)(b * NT + t) * UP1 + u) * VOCAB + wc * 64 + l15;
            #pragma unroll
            for (int nt = 0; nt < 4; ++nt)
                orow[nt * 16] = valid ? (acc[mt][nt][r4] + bj[nt]) : 0.f;
        }
    }
}

// ---------------------------------------------------------------------------
extern "C" void kernel_launch(void* const* d_in, const int* in_sizes, int n_in,
                              void* d_out, int out_size, void* d_ws, size_t ws_size,
                              hipStream_t stream) {
    (void)in_sizes; (void)n_in; (void)out_size; (void)ws_size;
    const float* enc     = (const float*)d_in[0];
    const int*   esz     = (const int*)d_in[1];
    const int*   targets = (const int*)d_in[2];
    const int*   tsz     = (const int*)d_in[3];
    const float* emb     = (const float*)d_in[4];
    const float* W1      = (const float*)d_in[5];
    const float* b1      = (const float*)d_in[6];
    const float* W2      = (const float*)d_in[7];
    const float* b2      = (const float*)d_in[8];
    const float* Wj1     = (const float*)d_in[9];
    const float* bj1     = (const float*)d_in[10];
    const float* Wj2     = (const float*)d_in[11];
    const float* bj2     = (const float*)d_in[12];
    float* out = (float*)d_out;

    // workspace layout
    float* eproj = (float*)d_ws;                                   // 8 MB
    float* pproj = eproj + (size_t)NB * NT * JOIND;                // 1.04 MB
    unsigned short* WjF = (unsigned short*)(pproj + (size_t)NB * UP1 * JOIND);
    unsigned short* WeF = WjF + 65536;                             // 128KB | 512KB

    prep_weights<<<1280, 256, 0, stream>>>(Wj2, Wj1, WjF, WeF);
    fused_pe<<<193, 256, 0, stream>>>(targets, tsz, emb, W1, b1, W2, b2,
                                      Wj1, bj1, pproj,
                                      enc, WeF, esz, eproj);
    joint_kernel<<<2304, 256, 0, stream>>>(eproj, pproj, WjF,
                                           bj2, esz, tsz, out);
}

// Round 10
// 225.172 us; speedup vs baseline: 1.1021x; 1.1021x over previous
//
#include <hip/hip_runtime.h>

// FFNN Transducer fused forward — R10 (= R9 resubmit; R9 bench was an infra
// acquisition timeout, source never ran).
// = R7 structure (R8's dbuf + pred restructure REVERTED: regressed +15.6us)
// + joint switched to SINGLE RNE-fp16 A term (h split was VALU-bound:
//   ~160 VALU vs ~155 MFMA cyc/chunk/wave; now ~96 VALU + 16 MFMA).
// enc stays fp16 2-term (accuracy of eproj feeds everything; enc is cheap).
// Inputs (setup_inputs order):
//  0 encoder_states (8,512,512) f32     1 encoder_states_size (8) i32
//  2 targets (8,64) i32                 3 targets_size (8) i32
//  4 emb (128,128) f32                  5 W1 (256,256)  6 b1 (256)
//  7 W2 (256,256)  8 b2 (256)           9 Wj1 (768,512) 10 bj1 (512)
// 11 Wj2 (512,128) 12 bj2 (128)
// Output: (8,512,65,128) f32, masked.

#define VOCAB 128
#define EMBD  128
#define ENCD  512
#define PREDD 256
#define JOIND 512
#define NB    8
#define NT    512
#define NUT   64
#define UP1   65
#define PRROWS 4

typedef __fp16   pk16x2 __attribute__((ext_vector_type(2)));   // cvt_pkrtz ret
typedef _Float16 f16x8  __attribute__((ext_vector_type(8)));
typedef float    f32x4  __attribute__((ext_vector_type(4)));

__device__ __forceinline__ float frelu(float x) { return x > 0.f ? x : 0.f; }

// Split two f32 into packed fp16 hi (RTZ) + fp16 lo (RTZ of residual).
__device__ __forceinline__ void splitf16_2(float x0, float x1,
                                           unsigned& hi, unsigned& lo) {
    pk16x2 h = __builtin_amdgcn_cvt_pkrtz(x0, x1);
    float r0 = x0 - (float)h.x;
    float r1 = x1 - (float)h.y;
    pk16x2 l = __builtin_amdgcn_cvt_pkrtz(r0, r1);
    __builtin_memcpy(&hi, &h, 4);
    __builtin_memcpy(&lo, &l, 4);
}

// ---------------------------------------------------------------------------
// Prep: swizzled single-fp16 B-images for joint (Wj2^T) and enc (We^T).
// Per 32-k chunk: row n holds 4 16B slots (8 f16); physical slot p stores
// k-slot (p ^ (n&3)). Consumers stage with a linear aligned copy.
// ---------------------------------------------------------------------------
__global__ __launch_bounds__(256) void prep_weights(
    const float* __restrict__ Wj2, const float* __restrict__ Wj1,
    unsigned short* __restrict__ WjF, unsigned short* __restrict__ WeF)
{
    const int idx = blockIdx.x * 256 + threadIdx.x;   // 0..327679
    float x; unsigned short* dst;
    if (idx < VOCAB * JOIND) {
        const int c = idx >> 12, rem = idx & 4095;
        const int n = rem >> 5, p = (rem >> 3) & 3, e = rem & 7;
        const int k = c * 32 + ((p ^ (n & 3)) << 3) + e;
        x = Wj2[k * VOCAB + n];
        dst = WjF + idx;
    } else {
        const int j = idx - VOCAB * JOIND;            // 0..262143
        const int ct = j >> 16, rem1 = j & 65535;
        const int c = rem1 >> 12, rem = rem1 & 4095;
        const int nl = rem >> 5, p = (rem >> 3) & 3, e = rem & 7;
        const int n = ct * 128 + nl;
        const int k = c * 32 + ((p ^ (nl & 3)) << 3) + e;
        x = Wj1[(size_t)k * JOIND + n];
        dst = WeF + j;
    }
    const _Float16 h = (_Float16)x;                   // RNE
    unsigned short bits; __builtin_memcpy(&bits, &h, 2);
    *dst = bits;
}

// ---------------------------------------------------------------------------
// Fused pred-net + enc_proj: bx<130 -> pred (4 rows each), else enc tile.
// (R7 version, verbatim.)
// ---------------------------------------------------------------------------
__global__ __launch_bounds__(256, 3) void fused_pe(
    const int* __restrict__ targets, const int* __restrict__ tsz,
    const float* __restrict__ emb,
    const float* __restrict__ W1, const float* __restrict__ b1,
    const float* __restrict__ W2, const float* __restrict__ b2,
    const float* __restrict__ Wj1, const float* __restrict__ bj1,
    float* __restrict__ pproj,
    const float* __restrict__ A,
    const unsigned short* __restrict__ WeF,
    const int* __restrict__ esz, float* __restrict__ eproj)
{
    __shared__ __align__(16) unsigned char smem[24576];
    const int tid = threadIdx.x;

    if (blockIdx.x < 130) {
        // ================= pred part =================
        float (*eS)[256] = (float(*)[256])smem;
        float (*pS)[256] = (float(*)[256])(smem + 4096);
        const int r0 = blockIdx.x * PRROWS;

        bool anyLive = false;
        #pragma unroll
        for (int i = 0; i < PRROWS; ++i) {
            const int row = r0 + i, b = row / UP1, u = row % UP1;
            anyLive = anyLive || (u <= tsz[b]);
        }
        if (!anyLive) return;

        #pragma unroll
        for (int i = 0; i < PRROWS; ++i) {
            const int row = r0 + i, b = row / UP1, u = row % UP1;
            const int c0 = (u >= 1) ? targets[b * NUT + u - 1] : (VOCAB - 1);
            const int c1 = (u >= 2) ? targets[b * NUT + u - 2] : (VOCAB - 1);
            eS[i][tid] = (tid < EMBD) ? emb[c0 * EMBD + tid]
                                      : emb[c1 * EMBD + (tid - EMBD)];
        }
        __syncthreads();
        {   // layer 1
            float f[PRROWS] = {};
            for (int k = 0; k < 256; k += 4) {
                const float w0 = W1[(k + 0) * PREDD + tid];
                const float w1 = W1[(k + 1) * PREDD + tid];
                const float w2 = W1[(k + 2) * PREDD + tid];
                const float w3 = W1[(k + 3) * PREDD + tid];
                #pragma unroll
                for (int i = 0; i < PRROWS; ++i) {
                    const float4 e = *(const float4*)&eS[i][k];
                    f[i] = fmaf(e.x, w0, fmaf(e.y, w1, fmaf(e.z, w2, fmaf(e.w, w3, f[i]))));
                }
            }
            const float bb = b1[tid];
            #pragma unroll
            for (int i = 0; i < PRROWS; ++i) pS[i][tid] = frelu(f[i] + bb);
        }
        __syncthreads();
        {   // layer 2 -> eS
            float f[PRROWS] = {};
            for (int k = 0; k < 256; k += 4) {
                const float w0 = W2[(k + 0) * PREDD + tid];
                const float w1 = W2[(k + 1) * PREDD + tid];
                const float w2 = W2[(k + 2) * PREDD + tid];
                const float w3 = W2[(k + 3) * PREDD + tid];
                #pragma unroll
                for (int i = 0; i < PRROWS; ++i) {
                    const float4 p = *(const float4*)&pS[i][k];
                    f[i] = fmaf(p.x, w0, fmaf(p.y, w1, fmaf(p.z, w2, fmaf(p.w, w3, f[i]))));
                }
            }
            const float bb = b2[tid];
            #pragma unroll
            for (int i = 0; i < PRROWS; ++i) eS[i][tid] = frelu(f[i] + bb);
        }
        __syncthreads();
        #pragma unroll
        for (int h = 0; h < 2; ++h) {   // projection, 512 cols
            const int col = tid + h * 256;
            float g[PRROWS] = {};
            for (int k = 0; k < 256; k += 4) {
                const float w0 = Wj1[(size_t)(ENCD + k + 0) * JOIND + col];
                const float w1 = Wj1[(size_t)(ENCD + k + 1) * JOIND + col];
                const float w2 = Wj1[(size_t)(ENCD + k + 2) * JOIND + col];
                const float w3 = Wj1[(size_t)(ENCD + k + 3) * JOIND + col];
                #pragma unroll
                for (int i = 0; i < PRROWS; ++i) {
                    const float4 qv = *(const float4*)&eS[i][k];
                    g[i] = fmaf(qv.x, w0, fmaf(qv.y, w1, fmaf(qv.z, w2, fmaf(qv.w, w3, g[i]))));
                }
            }
            const float bb = bj1[col];
            #pragma unroll
            for (int i = 0; i < PRROWS; ++i)
                pproj[(size_t)(r0 + i) * JOIND + col] = g[i] + bb;
        }
        return;
    }

    // ================= enc part (fp16 2-term, prefetch) =================
    unsigned short* AhS = (unsigned short*)smem;             // 8KB
    unsigned short* AlS = (unsigned short*)(smem + 8192);    // 8KB
    unsigned short* BhS = (unsigned short*)(smem + 16384);   // 8KB

    const int bxe = blockIdx.x - 130;
    const int rTile = bxe >> 2;                   // 0..31
    const int ct = bxe & 3;
    const int b = rTile >> 2;
    const int t0 = (rTile & 3) * 128;
    if (t0 >= esz[b]) return;

    const int q = tid & 7;
    const float* ap[4]; int offA[4];
    #pragma unroll
    for (int p = 0; p < 4; ++p) {
        const int r = p * 32 + (tid >> 3);
        ap[p] = A + (size_t)(rTile * 128 + r) * ENCD + q * 4;
        offA[p] = r * 32 + (((q >> 1) ^ (r & 3)) << 3) + ((q & 1) << 2);
    }
    const size_t wbase = (size_t)ct * 65536;      // f16 units

    const int lane = tid & 63, w = tid >> 6;
    const int wr = w >> 1, wc = w & 1;
    const int l15 = lane & 15, lj = lane >> 4;
    const int sw = lj ^ (l15 & 3);

    f32x4 acc[4][4];
    #pragma unroll
    for (int mt = 0; mt < 4; ++mt)
        #pragma unroll
        for (int nt = 0; nt < 4; ++nt)
            acc[mt][nt] = (f32x4){0.f, 0.f, 0.f, 0.f};

    float4 aReg[4]; uint4 bReg0, bReg1;
    {   // prologue load chunk 0
        #pragma unroll
        for (int p = 0; p < 4; ++p) aReg[p] = *(const float4*)(ap[p]);
        bReg0 = *(const uint4*)&WeF[wbase + (size_t)tid * 8];
        bReg1 = *(const uint4*)&WeF[wbase + (size_t)(tid + 256) * 8];
    }

    for (int c = 0; c < 16; ++c) {
        __syncthreads();
        // STORE staged regs -> LDS
        #pragma unroll
        for (int p = 0; p < 4; ++p) {
            unsigned h0, h1, l0, l1;
            splitf16_2(aReg[p].x, aReg[p].y, h0, l0);
            splitf16_2(aReg[p].z, aReg[p].w, h1, l1);
            *(uint2*)&AhS[offA[p]] = make_uint2(h0, h1);
            *(uint2*)&AlS[offA[p]] = make_uint2(l0, l1);
        }
        *(uint4*)&BhS[tid * 8] = bReg0;
        *(uint4*)&BhS[(tid + 256) * 8] = bReg1;
        __syncthreads();
        if (c < 15) {   // prefetch next chunk
            const int kc = (c + 1) * 32;
            #pragma unroll
            for (int p = 0; p < 4; ++p) aReg[p] = *(const float4*)(ap[p] + kc);
            const size_t g = wbase + ((size_t)(c + 1) << 12);
            bReg0 = *(const uint4*)&WeF[g + (size_t)tid * 8];
            bReg1 = *(const uint4*)&WeF[g + (size_t)(tid + 256) * 8];
        }
        // COMPUTE chunk c
        f16x8 bh[4];
        #pragma unroll
        for (int nt = 0; nt < 4; ++nt) {
            const int n = wc * 64 + nt * 16 + l15;
            bh[nt] = *(const f16x8*)&BhS[n * 32 + (sw << 3)];
        }
        #pragma unroll
        for (int mt = 0; mt < 4; ++mt) {
            const int m = wr * 64 + mt * 16 + l15;
            const int off = m * 32 + (sw << 3);
            const f16x8 ah = *(const f16x8*)&AhS[off];
            const f16x8 al = *(const f16x8*)&AlS[off];
            #pragma unroll
            for (int nt = 0; nt < 4; ++nt) {
                acc[mt][nt] = __builtin_amdgcn_mfma_f32_16x16x32_f16(ah, bh[nt], acc[mt][nt], 0, 0, 0);
                acc[mt][nt] = __builtin_amdgcn_mfma_f32_16x16x32_f16(al, bh[nt], acc[mt][nt], 0, 0, 0);
            }
        }
    }
    #pragma unroll
    for (int mt = 0; mt < 4; ++mt)
        #pragma unroll
        for (int r4 = 0; r4 < 4; ++r4) {
            const int row = wr * 64 + mt * 16 + lj * 4 + r4;
            float* dst = eproj + (size_t)(rTile * 128 + row) * JOIND
                       + ct * 128 + wc * 64 + l15;
            #pragma unroll
            for (int nt = 0; nt < 4; ++nt) dst[nt * 16] = acc[mt][nt][r4];
        }
}

// ---------------------------------------------------------------------------
// Joint: 1-D grid 2304, XCD remap (one batch per XCD).
// Block = 128 rows (16t x 8u) x 128 v; 4 waves (2x2) of 64x64.
// e + p staged once per chunk (f32, XOR-swizzled); h = relu(e+p) converted to
// SINGLE RNE fp16 in-register; B single fp16 image. 16 MFMA/chunk.
// ---------------------------------------------------------------------------
__global__ __launch_bounds__(256, 3) void joint_kernel(
    const float* __restrict__ Eproj, const float* __restrict__ Pproj,
    const unsigned short* __restrict__ WjF,
    const float* __restrict__ bj2,
    const int* __restrict__ esz, const int* __restrict__ tsz,
    float* __restrict__ out)
{
    const int flat = blockIdx.x;                      // 0..2303
    const int logical = (flat & 7) * 288 + (flat >> 3);
    const int b  = logical / 288;
    const int rem = logical - b * 288;
    const int t0 = (rem / 9) * 16;
    const int u0 = (rem % 9) * 8;
    const int tid = threadIdx.x;
    const int es = esz[b], ts = tsz[b];
    const int nu = (UP1 - u0 < 8) ? (UP1 - u0) : 8;   // 8 or 1

    if (t0 >= es || u0 > ts) {   // fully masked -> zero fill
        const float4 z = {0.f, 0.f, 0.f, 0.f};
        const int total = 16 * nu * 32;               // float4 count
        for (int idx = tid; idx < total; idx += 256) {
            const int slot = idx & 31;
            const int rr = idx >> 5;
            const int tt = (nu == 8) ? (rr >> 3) : rr;
            const int uu = (nu == 8) ? (rr & 7) : 0;
            *(float4*)&out[(((size_t)(b * NT + t0 + tt) * UP1 + (u0 + uu)) << 7) + slot * 4] = z;
        }
        return;
    }

    __shared__ __align__(16) unsigned short BhS[128 * 32];  // 8KB fp16
    __shared__ __align__(16) float eS[16 * 32];             // 2KB
    __shared__ __align__(16) float pS[8 * 32];              // 1KB

    // staging assignments
    const int erow = tid >> 3, es8 = tid & 7;               // tid < 128
    const float* egp = Eproj + ((size_t)(b * NT + t0 + (erow & 15))) * JOIND + es8 * 4;
    float* elp = eS + (erow & 15) * 32 + ((es8 ^ (erow & 7)) << 2);
    const int prow = (tid >> 3) & 7, ps8 = tid & 7;         // tid in [128,192)
    int pu = u0 + prow; if (pu > NUT) pu = NUT;
    const float* pgp = Pproj + ((size_t)(b * UP1 + pu)) * JOIND + ps8 * 4;
    float* plp = pS + prow * 32 + ((ps8 ^ (prow & 7)) << 2);

    const int lane = tid & 63, w = tid >> 6;
    const int wr = w >> 1, wc = w & 1;
    const int l15 = lane & 15, lj = lane >> 4;
    const int sw = lj ^ (l15 & 3);
    const int urow = l15 & 7;
    const int po = urow * 32 + (((lj << 1) ^ (urow & 7)) << 2);
    int eo[4];
    #pragma unroll
    for (int mt = 0; mt < 4; ++mt) {
        const int trow = wr * 8 + mt * 2 + (l15 >> 3);
        eo[mt] = trow * 32 + (((lj << 1) ^ (trow & 7)) << 2);
    }
    int bo[4];
    #pragma unroll
    for (int nt = 0; nt < 4; ++nt)
        bo[nt] = (wc * 64 + nt * 16 + l15) * 32 + (sw << 3);

    f32x4 acc[4][4];
    #pragma unroll
    for (int mt = 0; mt < 4; ++mt)
        #pragma unroll
        for (int nt = 0; nt < 4; ++nt)
            acc[mt][nt] = (f32x4){0.f, 0.f, 0.f, 0.f};

    float4 aReg; uint4 bReg0, bReg1;
    {   // prologue load chunk 0
        if (tid < 128)       aReg = *(const float4*)egp;
        else if (tid < 192)  aReg = *(const float4*)pgp;
        bReg0 = *(const uint4*)&WjF[(size_t)tid * 8];
        bReg1 = *(const uint4*)&WjF[(size_t)(tid + 256) * 8];
    }

    for (int c = 0; c < 16; ++c) {
        __syncthreads();
        // STORE staged regs -> LDS
        if (tid < 128)      *(float4*)elp = aReg;
        else if (tid < 192) *(float4*)plp = aReg;
        *(uint4*)&BhS[tid * 8] = bReg0;
        *(uint4*)&BhS[(tid + 256) * 8] = bReg1;
        __syncthreads();
        if (c < 15) {   // prefetch next chunk
            const int kc = (c + 1) * 32;
            if (tid < 128)      aReg = *(const float4*)(egp + kc);
            else if (tid < 192) aReg = *(const float4*)(pgp + kc);
            const size_t g = (size_t)(c + 1) << 12;
            bReg0 = *(const uint4*)&WjF[g + (size_t)tid * 8];
            bReg1 = *(const uint4*)&WjF[g + (size_t)(tid + 256) * 8];
        }
        // COMPUTE chunk c — single RNE fp16 A term
        f16x8 bh[4];
        #pragma unroll
        for (int nt = 0; nt < 4; ++nt)
            bh[nt] = *(const f16x8*)&BhS[bo[nt]];
        const float4 pf0 = *(const float4*)&pS[po];
        const float4 pf1 = *(const float4*)&pS[po ^ 4];
        #pragma unroll
        for (int mt = 0; mt < 4; ++mt) {
            const float4 ef0 = *(const float4*)&eS[eo[mt]];
            const float4 ef1 = *(const float4*)&eS[eo[mt] ^ 4];
            f16x8 ah;
            ah[0] = (_Float16)frelu(ef0.x + pf0.x);
            ah[1] = (_Float16)frelu(ef0.y + pf0.y);
            ah[2] = (_Float16)frelu(ef0.z + pf0.z);
            ah[3] = (_Float16)frelu(ef0.w + pf0.w);
            ah[4] = (_Float16)frelu(ef1.x + pf1.x);
            ah[5] = (_Float16)frelu(ef1.y + pf1.y);
            ah[6] = (_Float16)frelu(ef1.z + pf1.z);
            ah[7] = (_Float16)frelu(ef1.w + pf1.w);
            #pragma unroll
            for (int nt = 0; nt < 4; ++nt)
                acc[mt][nt] = __builtin_amdgcn_mfma_f32_16x16x32_f16(ah, bh[nt], acc[mt][nt], 0, 0, 0);
        }
    }

    // epilogue: +bj2, mask, store (D layout: col=lane&15, row=lj*4+reg)
    float bj[4];
    #pragma unroll
    for (int nt = 0; nt < 4; ++nt) bj[nt] = bj2[wc * 64 + nt * 16 + l15];

    #pragma unroll
    for (int mt = 0; mt < 4; ++mt) {
        #pragma unroll
        for (int r4 = 0; r4 < 4; ++r4) {
            const int row = wr * 64 + mt * 16 + lj * 4 + r4;
            const int t = t0 + (row >> 3);
            const int u = u0 + (row & 7);
            if (u >= UP1) continue;                  // u0=64 tiles only
            const bool valid = (t < es) && (u <= ts);
            float* __restrict__ orow =
                out + ((size_t)(b * NT + t) * UP1 + u) * VOCAB + wc * 64 + l15;
            #pragma unroll
            for (int nt = 0; nt < 4; ++nt)
                orow[nt * 16] = valid ? (acc[mt][nt][r4] + bj[nt]) : 0.f;
        }
    }
}

// ---------------------------------------------------------------------------
extern "C" void kernel_launch(void* const* d_in, const int* in_sizes, int n_in,
                              void* d_out, int out_size, void* d_ws, size_t ws_size,
                              hipStream_t stream) {
    (void)in_sizes; (void)n_in; (void)out_size; (void)ws_size;
    const float* enc     = (const float*)d_in[0];
    const int*   esz     = (const int*)d_in[1];
    const int*   targets = (const int*)d_in[2];
    const int*   tsz     = (const int*)d_in[3];
    const float* emb     = (const float*)d_in[4];
    const float* W1      = (const float*)d_in[5];
    const float* b1      = (const float*)d_in[6];
    const float* W2      = (const float*)d_in[7];
    const float* b2      = (const float*)d_in[8];
    const float* Wj1     = (const float*)d_in[9];
    const float* bj1     = (const float*)d_in[10];
    const float* Wj2     = (const float*)d_in[11];
    const float* bj2     = (const float*)d_in[12];
    float* out = (float*)d_out;

    // workspace layout
    float* eproj = (float*)d_ws;                                   // 8 MB
    float* pproj = eproj + (size_t)NB * NT * JOIND;                // 1.04 MB
    unsigned short* WjF = (unsigned short*)(pproj + (size_t)NB * UP1 * JOIND);
    unsigned short* WeF = WjF + 65536;                             // 128KB | 512KB

    prep_weights<<<1280, 256, 0, stream>>>(Wj2, Wj1, WjF, WeF);
    fused_pe<<<258, 256, 0, stream>>>(targets, tsz, emb, W1, b1, W2, b2,
                                      Wj1, bj1, pproj,
                                      enc, WeF, esz, eproj);
    joint_kernel<<<2304, 256, 0, stream>>>(eproj, pproj, WjF,
                                           bj2, esz, tsz, out);
}

// Round 12
// 220.867 us; speedup vs baseline: 1.1236x; 1.0195x over previous
//
#include <hip/hip_runtime.h>

// FFNN Transducer fused forward — R12 (= R11 resubmit; R11 bench was an infra
// acquisition timeout, source never ran).
// = R10 + joint wave layout 2x2 -> 4x1 (wave = 32 rows x 128 cols):
//   h-conversion VALU was duplicated across the 2 column-waves (96 ops/chunk/
//   wave, 2x redundant). Now each row converted once: 48 ops/chunk/wave.
//   Same 16 MFMA/chunk/wave. bj2 folded into accumulator init.
// enc stays fp16 2-term; pred unchanged (R8 churn lesson).
// Inputs (setup_inputs order):
//  0 encoder_states (8,512,512) f32     1 encoder_states_size (8) i32
//  2 targets (8,64) i32                 3 targets_size (8) i32
//  4 emb (128,128) f32                  5 W1 (256,256)  6 b1 (256)
//  7 W2 (256,256)  8 b2 (256)           9 Wj1 (768,512) 10 bj1 (512)
// 11 Wj2 (512,128) 12 bj2 (128)
// Output: (8,512,65,128) f32, masked.

#define VOCAB 128
#define EMBD  128
#define ENCD  512
#define PREDD 256
#define JOIND 512
#define NB    8
#define NT    512
#define NUT   64
#define UP1   65
#define PRROWS 4

typedef __fp16   pk16x2 __attribute__((ext_vector_type(2)));   // cvt_pkrtz ret
typedef _Float16 f16x8  __attribute__((ext_vector_type(8)));
typedef float    f32x4  __attribute__((ext_vector_type(4)));

__device__ __forceinline__ float frelu(float x) { return x > 0.f ? x : 0.f; }

// Split two f32 into packed fp16 hi (RTZ) + fp16 lo (RTZ of residual).
__device__ __forceinline__ void splitf16_2(float x0, float x1,
                                           unsigned& hi, unsigned& lo) {
    pk16x2 h = __builtin_amdgcn_cvt_pkrtz(x0, x1);
    float r0 = x0 - (float)h.x;
    float r1 = x1 - (float)h.y;
    pk16x2 l = __builtin_amdgcn_cvt_pkrtz(r0, r1);
    __builtin_memcpy(&hi, &h, 4);
    __builtin_memcpy(&lo, &l, 4);
}

// ---------------------------------------------------------------------------
// Prep: swizzled single-fp16 B-images for joint (Wj2^T) and enc (We^T).
// Per 32-k chunk: row n holds 4 16B slots (8 f16); physical slot p stores
// k-slot (p ^ (n&3)). Consumers stage with a linear aligned copy.
// ---------------------------------------------------------------------------
__global__ __launch_bounds__(256) void prep_weights(
    const float* __restrict__ Wj2, const float* __restrict__ Wj1,
    unsigned short* __restrict__ WjF, unsigned short* __restrict__ WeF)
{
    const int idx = blockIdx.x * 256 + threadIdx.x;   // 0..327679
    float x; unsigned short* dst;
    if (idx < VOCAB * JOIND) {
        const int c = idx >> 12, rem = idx & 4095;
        const int n = rem >> 5, p = (rem >> 3) & 3, e = rem & 7;
        const int k = c * 32 + ((p ^ (n & 3)) << 3) + e;
        x = Wj2[k * VOCAB + n];
        dst = WjF + idx;
    } else {
        const int j = idx - VOCAB * JOIND;            // 0..262143
        const int ct = j >> 16, rem1 = j & 65535;
        const int c = rem1 >> 12, rem = rem1 & 4095;
        const int nl = rem >> 5, p = (rem >> 3) & 3, e = rem & 7;
        const int n = ct * 128 + nl;
        const int k = c * 32 + ((p ^ (nl & 3)) << 3) + e;
        x = Wj1[(size_t)k * JOIND + n];
        dst = WeF + j;
    }
    const _Float16 h = (_Float16)x;                   // RNE
    unsigned short bits; __builtin_memcpy(&bits, &h, 2);
    *dst = bits;
}

// ---------------------------------------------------------------------------
// Fused pred-net + enc_proj: bx<130 -> pred (4 rows each), else enc tile.
// (R7 version, verbatim.)
// ---------------------------------------------------------------------------
__global__ __launch_bounds__(256, 3) void fused_pe(
    const int* __restrict__ targets, const int* __restrict__ tsz,
    const float* __restrict__ emb,
    const float* __restrict__ W1, const float* __restrict__ b1,
    const float* __restrict__ W2, const float* __restrict__ b2,
    const float* __restrict__ Wj1, const float* __restrict__ bj1,
    float* __restrict__ pproj,
    const float* __restrict__ A,
    const unsigned short* __restrict__ WeF,
    const int* __restrict__ esz, float* __restrict__ eproj)
{
    __shared__ __align__(16) unsigned char smem[24576];
    const int tid = threadIdx.x;

    if (blockIdx.x < 130) {
        // ================= pred part =================
        float (*eS)[256] = (float(*)[256])smem;
        float (*pS)[256] = (float(*)[256])(smem + 4096);
        const int r0 = blockIdx.x * PRROWS;

        bool anyLive = false;
        #pragma unroll
        for (int i = 0; i < PRROWS; ++i) {
            const int row = r0 + i, b = row / UP1, u = row % UP1;
            anyLive = anyLive || (u <= tsz[b]);
        }
        if (!anyLive) return;

        #pragma unroll
        for (int i = 0; i < PRROWS; ++i) {
            const int row = r0 + i, b = row / UP1, u = row % UP1;
            const int c0 = (u >= 1) ? targets[b * NUT + u - 1] : (VOCAB - 1);
            const int c1 = (u >= 2) ? targets[b * NUT + u - 2] : (VOCAB - 1);
            eS[i][tid] = (tid < EMBD) ? emb[c0 * EMBD + tid]
                                      : emb[c1 * EMBD + (tid - EMBD)];
        }
        __syncthreads();
        {   // layer 1
            float f[PRROWS] = {};
            for (int k = 0; k < 256; k += 4) {
                const float w0 = W1[(k + 0) * PREDD + tid];
                const float w1 = W1[(k + 1) * PREDD + tid];
                const float w2 = W1[(k + 2) * PREDD + tid];
                const float w3 = W1[(k + 3) * PREDD + tid];
                #pragma unroll
                for (int i = 0; i < PRROWS; ++i) {
                    const float4 e = *(const float4*)&eS[i][k];
                    f[i] = fmaf(e.x, w0, fmaf(e.y, w1, fmaf(e.z, w2, fmaf(e.w, w3, f[i]))));
                }
            }
            const float bb = b1[tid];
            #pragma unroll
            for (int i = 0; i < PRROWS; ++i) pS[i][tid] = frelu(f[i] + bb);
        }
        __syncthreads();
        {   // layer 2 -> eS
            float f[PRROWS] = {};
            for (int k = 0; k < 256; k += 4) {
                const float w0 = W2[(k + 0) * PREDD + tid];
                const float w1 = W2[(k + 1) * PREDD + tid];
                const float w2 = W2[(k + 2) * PREDD + tid];
                const float w3 = W2[(k + 3) * PREDD + tid];
                #pragma unroll
                for (int i = 0; i < PRROWS; ++i) {
                    const float4 p = *(const float4*)&pS[i][k];
                    f[i] = fmaf(p.x, w0, fmaf(p.y, w1, fmaf(p.z, w2, fmaf(p.w, w3, f[i]))));
                }
            }
            const float bb = b2[tid];
            #pragma unroll
            for (int i = 0; i < PRROWS; ++i) eS[i][tid] = frelu(f[i] + bb);
        }
        __syncthreads();
        #pragma unroll
        for (int h = 0; h < 2; ++h) {   // projection, 512 cols
            const int col = tid + h * 256;
            float g[PRROWS] = {};
            for (int k = 0; k < 256; k += 4) {
                const float w0 = Wj1[(size_t)(ENCD + k + 0) * JOIND + col];
                const float w1 = Wj1[(size_t)(ENCD + k + 1) * JOIND + col];
                const float w2 = Wj1[(size_t)(ENCD + k + 2) * JOIND + col];
                const float w3 = Wj1[(size_t)(ENCD + k + 3) * JOIND + col];
                #pragma unroll
                for (int i = 0; i < PRROWS; ++i) {
                    const float4 qv = *(const float4*)&eS[i][k];
                    g[i] = fmaf(qv.x, w0, fmaf(qv.y, w1, fmaf(qv.z, w2, fmaf(qv.w, w3, g[i]))));
                }
            }
            const float bb = bj1[col];
            #pragma unroll
            for (int i = 0; i < PRROWS; ++i)
                pproj[(size_t)(r0 + i) * JOIND + col] = g[i] + bb;
        }
        return;
    }

    // ================= enc part (fp16 2-term, prefetch) =================
    unsigned short* AhS = (unsigned short*)smem;             // 8KB
    unsigned short* AlS = (unsigned short*)(smem + 8192);    // 8KB
    unsigned short* BhS = (unsigned short*)(smem + 16384);   // 8KB

    const int bxe = blockIdx.x - 130;
    const int rTile = bxe >> 2;                   // 0..31
    const int ct = bxe & 3;
    const int b = rTile >> 2;
    const int t0 = (rTile & 3) * 128;
    if (t0 >= esz[b]) return;

    const int q = tid & 7;
    const float* ap[4]; int offA[4];
    #pragma unroll
    for (int p = 0; p < 4; ++p) {
        const int r = p * 32 + (tid >> 3);
        ap[p] = A + (size_t)(rTile * 128 + r) * ENCD + q * 4;
        offA[p] = r * 32 + (((q >> 1) ^ (r & 3)) << 3) + ((q & 1) << 2);
    }
    const size_t wbase = (size_t)ct * 65536;      // f16 units

    const int lane = tid & 63, w = tid >> 6;
    const int wr = w >> 1, wc = w & 1;
    const int l15 = lane & 15, lj = lane >> 4;
    const int sw = lj ^ (l15 & 3);

    f32x4 acc[4][4];
    #pragma unroll
    for (int mt = 0; mt < 4; ++mt)
        #pragma unroll
        for (int nt = 0; nt < 4; ++nt)
            acc[mt][nt] = (f32x4){0.f, 0.f, 0.f, 0.f};

    float4 aReg[4]; uint4 bReg0, bReg1;
    {   // prologue load chunk 0
        #pragma unroll
        for (int p = 0; p < 4; ++p) aReg[p] = *(const float4*)(ap[p]);
        bReg0 = *(const uint4*)&WeF[wbase + (size_t)tid * 8];
        bReg1 = *(const uint4*)&WeF[wbase + (size_t)(tid + 256) * 8];
    }

    for (int c = 0; c < 16; ++c) {
        __syncthreads();
        // STORE staged regs -> LDS
        #pragma unroll
        for (int p = 0; p < 4; ++p) {
            unsigned h0, h1, l0, l1;
            splitf16_2(aReg[p].x, aReg[p].y, h0, l0);
            splitf16_2(aReg[p].z, aReg[p].w, h1, l1);
            *(uint2*)&AhS[offA[p]] = make_uint2(h0, h1);
            *(uint2*)&AlS[offA[p]] = make_uint2(l0, l1);
        }
        *(uint4*)&BhS[tid * 8] = bReg0;
        *(uint4*)&BhS[(tid + 256) * 8] = bReg1;
        __syncthreads();
        if (c < 15) {   // prefetch next chunk
            const int kc = (c + 1) * 32;
            #pragma unroll
            for (int p = 0; p < 4; ++p) aReg[p] = *(const float4*)(ap[p] + kc);
            const size_t g = wbase + ((size_t)(c + 1) << 12);
            bReg0 = *(const uint4*)&WeF[g + (size_t)tid * 8];
            bReg1 = *(const uint4*)&WeF[g + (size_t)(tid + 256) * 8];
        }
        // COMPUTE chunk c
        f16x8 bh[4];
        #pragma unroll
        for (int nt = 0; nt < 4; ++nt) {
            const int n = wc * 64 + nt * 16 + l15;
            bh[nt] = *(const f16x8*)&BhS[n * 32 + (sw << 3)];
        }
        #pragma unroll
        for (int mt = 0; mt < 4; ++mt) {
            const int m = wr * 64 + mt * 16 + l15;
            const int off = m * 32 + (sw << 3);
            const f16x8 ah = *(const f16x8*)&AhS[off];
            const f16x8 al = *(const f16x8*)&AlS[off];
            #pragma unroll
            for (int nt = 0; nt < 4; ++nt) {
                acc[mt][nt] = __builtin_amdgcn_mfma_f32_16x16x32_f16(ah, bh[nt], acc[mt][nt], 0, 0, 0);
                acc[mt][nt] = __builtin_amdgcn_mfma_f32_16x16x32_f16(al, bh[nt], acc[mt][nt], 0, 0, 0);
            }
        }
    }
    #pragma unroll
    for (int mt = 0; mt < 4; ++mt)
        #pragma unroll
        for (int r4 = 0; r4 < 4; ++r4) {
            const int row = wr * 64 + mt * 16 + lj * 4 + r4;
            float* dst = eproj + (size_t)(rTile * 128 + row) * JOIND
                       + ct * 128 + wc * 64 + l15;
            #pragma unroll
            for (int nt = 0; nt < 4; ++nt) dst[nt * 16] = acc[mt][nt][r4];
        }
}

// ---------------------------------------------------------------------------
// Joint: 1-D grid 2304, XCD remap (one batch per XCD).
// Block = 128 rows (16t x 8u) x 128 v; 4 waves, each 32 rows x 128 cols
// (h converted ONCE per row; was duplicated across 2 column-waves).
// e + p staged once per chunk (f32, XOR-swizzled); h -> single RNE fp16;
// B single fp16 image; bj2 pre-loaded into accumulator (C-in = bias).
// ---------------------------------------------------------------------------
__global__ __launch_bounds__(256, 3) void joint_kernel(
    const float* __restrict__ Eproj, const float* __restrict__ Pproj,
    const unsigned short* __restrict__ WjF,
    const float* __restrict__ bj2,
    const int* __restrict__ esz, const int* __restrict__ tsz,
    float* __restrict__ out)
{
    const int flat = blockIdx.x;                      // 0..2303
    const int logical = (flat & 7) * 288 + (flat >> 3);
    const int b  = logical / 288;
    const int rem = logical - b * 288;
    const int t0 = (rem / 9) * 16;
    const int u0 = (rem % 9) * 8;
    const int tid = threadIdx.x;
    const int es = esz[b], ts = tsz[b];
    const int nu = (UP1 - u0 < 8) ? (UP1 - u0) : 8;   // 8 or 1

    if (t0 >= es || u0 > ts) {   // fully masked -> zero fill
        const float4 z = {0.f, 0.f, 0.f, 0.f};
        const int total = 16 * nu * 32;               // float4 count
        for (int idx = tid; idx < total; idx += 256) {
            const int slot = idx & 31;
            const int rr = idx >> 5;
            const int tt = (nu == 8) ? (rr >> 3) : rr;
            const int uu = (nu == 8) ? (rr & 7) : 0;
            *(float4*)&out[(((size_t)(b * NT + t0 + tt) * UP1 + (u0 + uu)) << 7) + slot * 4] = z;
        }
        return;
    }

    __shared__ __align__(16) unsigned short BhS[128 * 32];  // 8KB fp16
    __shared__ __align__(16) float eS[16 * 32];             // 2KB
    __shared__ __align__(16) float pS[8 * 32];              // 1KB

    // staging assignments
    const int erow = tid >> 3, es8 = tid & 7;               // tid < 128
    const float* egp = Eproj + ((size_t)(b * NT + t0 + (erow & 15))) * JOIND + es8 * 4;
    float* elp = eS + (erow & 15) * 32 + ((es8 ^ (erow & 7)) << 2);
    const int prow = (tid >> 3) & 7, ps8 = tid & 7;         // tid in [128,192)
    int pu = u0 + prow; if (pu > NUT) pu = NUT;
    const float* pgp = Pproj + ((size_t)(b * UP1 + pu)) * JOIND + ps8 * 4;
    float* plp = pS + prow * 32 + ((ps8 ^ (prow & 7)) << 2);

    const int lane = tid & 63, w = tid >> 6;                // wave = 32r x 128c
    const int l15 = lane & 15, lj = lane >> 4;
    const int sw = lj ^ (l15 & 3);
    const int urow = l15 & 7;
    const int po = urow * 32 + (((lj << 1) ^ (urow & 7)) << 2);
    int eo[2];
    #pragma unroll
    for (int mt = 0; mt < 2; ++mt) {
        const int trow = w * 4 + mt * 2 + (l15 >> 3);
        eo[mt] = trow * 32 + (((lj << 1) ^ (trow & 7)) << 2);
    }
    int bo[8];
    #pragma unroll
    for (int nt = 0; nt < 8; ++nt)
        bo[nt] = (nt * 16 + l15) * 32 + (sw << 3);

    // accumulator pre-loaded with bj2 (C-in = bias; masked rows overwrite 0)
    f32x4 acc[2][8];
    #pragma unroll
    for (int nt = 0; nt < 8; ++nt) {
        const float bjv = bj2[nt * 16 + l15];
        acc[0][nt] = (f32x4){bjv, bjv, bjv, bjv};
        acc[1][nt] = (f32x4){bjv, bjv, bjv, bjv};
    }

    float4 aReg; uint4 bReg0, bReg1;
    {   // prologue load chunk 0
        if (tid < 128)       aReg = *(const float4*)egp;
        else if (tid < 192)  aReg = *(const float4*)pgp;
        bReg0 = *(const uint4*)&WjF[(size_t)tid * 8];
        bReg1 = *(const uint4*)&WjF[(size_t)(tid + 256) * 8];
    }

    for (int c = 0; c < 16; ++c) {
        __syncthreads();
        // STORE staged regs -> LDS
        if (tid < 128)      *(float4*)elp = aReg;
        else if (tid < 192) *(float4*)plp = aReg;
        *(uint4*)&BhS[tid * 8] = bReg0;
        *(uint4*)&BhS[(tid + 256) * 8] = bReg1;
        __syncthreads();
        if (c < 15) {   // prefetch next chunk
            const int kc = (c + 1) * 32;
            if (tid < 128)      aReg = *(const float4*)(egp + kc);
            else if (tid < 192) aReg = *(const float4*)(pgp + kc);
            const size_t g = (size_t)(c + 1) << 12;
            bReg0 = *(const uint4*)&WjF[g + (size_t)tid * 8];
            bReg1 = *(const uint4*)&WjF[g + (size_t)(tid + 256) * 8];
        }
        // COMPUTE chunk c — single RNE fp16 A, rows converted once per wave
        f16x8 bh[8];
        #pragma unroll
        for (int nt = 0; nt < 8; ++nt)
            bh[nt] = *(const f16x8*)&BhS[bo[nt]];
        const float4 pf0 = *(const float4*)&pS[po];
        const float4 pf1 = *(const float4*)&pS[po ^ 4];
        #pragma unroll
        for (int mt = 0; mt < 2; ++mt) {
            const float4 ef0 = *(const float4*)&eS[eo[mt]];
            const float4 ef1 = *(const float4*)&eS[eo[mt] ^ 4];
            f16x8 ah;
            ah[0] = (_Float16)frelu(ef0.x + pf0.x);
            ah[1] = (_Float16)frelu(ef0.y + pf0.y);
            ah[2] = (_Float16)frelu(ef0.z + pf0.z);
            ah[3] = (_Float16)frelu(ef0.w + pf0.w);
            ah[4] = (_Float16)frelu(ef1.x + pf1.x);
            ah[5] = (_Float16)frelu(ef1.y + pf1.y);
            ah[6] = (_Float16)frelu(ef1.z + pf1.z);
            ah[7] = (_Float16)frelu(ef1.w + pf1.w);
            #pragma unroll
            for (int nt = 0; nt < 8; ++nt)
                acc[mt][nt] = __builtin_amdgcn_mfma_f32_16x16x32_f16(ah, bh[nt], acc[mt][nt], 0, 0, 0);
        }
    }

    // epilogue: mask, store (D layout: col=lane&15, row=lj*4+reg). bias is in.
    #pragma unroll
    for (int mt = 0; mt < 2; ++mt) {
        #pragma unroll
        for (int r4 = 0; r4 < 4; ++r4) {
            const int row = w * 32 + mt * 16 + lj * 4 + r4;
            const int t = t0 + (row >> 3);
            const int u = u0 + (row & 7);
            if (u >= UP1) continue;                  // u0=64 tiles only
            const bool valid = (t < es) && (u <= ts);
            float* __restrict__ orow =
                out + ((size_t)(b * NT + t) * UP1 + u) * VOCAB + l15;
            #pragma unroll
            for (int nt = 0; nt < 8; ++nt)
                orow[nt * 16] = valid ? acc[mt][nt][r4] : 0.f;
        }
    }
}

// ---------------------------------------------------------------------------
extern "C" void kernel_launch(void* const* d_in, const int* in_sizes, int n_in,
                              void* d_out, int out_size, void* d_ws, size_t ws_size,
                              hipStream_t stream) {
    (void)in_sizes; (void)n_in; (void)out_size; (void)ws_size;
    const float* enc     = (const float*)d_in[0];
    const int*   esz     = (const int*)d_in[1];
    const int*   targets = (const int*)d_in[2];
    const int*   tsz     = (const int*)d_in[3];
    const float* emb     = (const float*)d_in[4];
    const float* W1      = (const float*)d_in[5];
    const float* b1      = (const float*)d_in[6];
    const float* W2      = (const float*)d_in[7];
    const float* b2      = (const float*)d_in[8];
    const float* Wj1     = (const float*)d_in[9];
    const float* bj1     = (const float*)d_in[10];
    const float* Wj2     = (const float*)d_in[11];
    const float* bj2     = (const float*)d_in[12];
    float* out = (float*)d_out;

    // workspace layout
    float* eproj = (float*)d_ws;                                   // 8 MB
    float* pproj = eproj + (size_t)NB * NT * JOIND;                // 1.04 MB
    unsigned short* WjF = (unsigned short*)(pproj + (size_t)NB * UP1 * JOIND);
    unsigned short* WeF = WjF + 65536;                             // 128KB | 512KB

    prep_weights<<<1280, 256, 0, stream>>>(Wj2, Wj1, WjF, WeF);
    fused_pe<<<258, 256, 0, stream>>>(targets, tsz, emb, W1, b1, W2, b2,
                                      Wj1, bj1, pproj,
                                      enc, WeF, esz, eproj);
    joint_kernel<<<2304, 256, 0, stream>>>(eproj, pproj, WjF,
                                           bj2, esz, tsz, out);
}

// Round 13
// 210.212 us; speedup vs baseline: 1.1805x; 1.0507x over previous
//
#include <hip/hip_runtime.h>

// FFNN Transducer fused forward — R13.
// = R12 + pred weights as fp16 images (prep-converted): pred was weight-
//   TRAFFIC bound (130 blocks x 1MB fp32 = 130MB L2/L3); fp16 halves it.
//   Pred keeps fp32 accumulate (load fp16 -> cvt -> fma).
// Joint (4x1 waves, single-fp16 A, bias-in-acc) and enc (fp16 2-term)
// unchanged from R12.
// Inputs (setup_inputs order):
//  0 encoder_states (8,512,512) f32     1 encoder_states_size (8) i32
//  2 targets (8,64) i32                 3 targets_size (8) i32
//  4 emb (128,128) f32                  5 W1 (256,256)  6 b1 (256)
//  7 W2 (256,256)  8 b2 (256)           9 Wj1 (768,512) 10 bj1 (512)
// 11 Wj2 (512,128) 12 bj2 (128)
// Output: (8,512,65,128) f32, masked.

#define VOCAB 128
#define EMBD  128
#define ENCD  512
#define PREDD 256
#define JOIND 512
#define NB    8
#define NT    512
#define NUT   64
#define UP1   65
#define PRROWS 4

typedef __fp16   pk16x2 __attribute__((ext_vector_type(2)));   // cvt_pkrtz ret
typedef _Float16 f16x8  __attribute__((ext_vector_type(8)));
typedef float    f32x4  __attribute__((ext_vector_type(4)));

__device__ __forceinline__ float frelu(float x) { return x > 0.f ? x : 0.f; }

// Split two f32 into packed fp16 hi (RTZ) + fp16 lo (RTZ of residual).
__device__ __forceinline__ void splitf16_2(float x0, float x1,
                                           unsigned& hi, unsigned& lo) {
    pk16x2 h = __builtin_amdgcn_cvt_pkrtz(x0, x1);
    float r0 = x0 - (float)h.x;
    float r1 = x1 - (float)h.y;
    pk16x2 l = __builtin_amdgcn_cvt_pkrtz(r0, r1);
    __builtin_memcpy(&hi, &h, 4);
    __builtin_memcpy(&lo, &l, 4);
}

// ---------------------------------------------------------------------------
// Prep: (a) swizzled fp16 B-images for joint (Wj2^T) and enc (We^T);
//       (b) flat fp16 images of pred weights W1, W2, Wp(=Wj1[512:768]).
// Grid: 2304 blocks x 256.
// ---------------------------------------------------------------------------
__global__ __launch_bounds__(256) void prep_weights(
    const float* __restrict__ Wj2, const float* __restrict__ Wj1,
    const float* __restrict__ W1, const float* __restrict__ W2,
    unsigned short* __restrict__ WjF, unsigned short* __restrict__ WeF,
    unsigned short* __restrict__ W1h, unsigned short* __restrict__ W2h,
    unsigned short* __restrict__ Wph)
{
    const int idx = blockIdx.x * 256 + threadIdx.x;   // 0..589823
    float x; unsigned short* dst;
    if (idx < 65536) {                                // WjF (swizzled)
        const int c = idx >> 12, rem = idx & 4095;
        const int n = rem >> 5, p = (rem >> 3) & 3, e = rem & 7;
        const int k = c * 32 + ((p ^ (n & 3)) << 3) + e;
        x = Wj2[k * VOCAB + n];
        dst = WjF + idx;
    } else if (idx < 327680) {                        // WeF (swizzled)
        const int j = idx - 65536;                    // 0..262143
        const int ct = j >> 16, rem1 = j & 65535;
        const int c = rem1 >> 12, rem = rem1 & 4095;
        const int nl = rem >> 5, p = (rem >> 3) & 3, e = rem & 7;
        const int n = ct * 128 + nl;
        const int k = c * 32 + ((p ^ (nl & 3)) << 3) + e;
        x = Wj1[(size_t)k * JOIND + n];
        dst = WeF + j;
    } else if (idx < 393216) {                        // W1h flat
        const int j = idx - 327680;
        x = W1[j];  dst = W1h + j;
    } else if (idx < 458752) {                        // W2h flat
        const int j = idx - 393216;
        x = W2[j];  dst = W2h + j;
    } else {                                          // Wph flat (256x512)
        const int j = idx - 458752;
        x = Wj1[(size_t)ENCD * JOIND + j];  dst = Wph + j;
    }
    const _Float16 h = (_Float16)x;                   // RNE
    unsigned short bits; __builtin_memcpy(&bits, &h, 2);
    *dst = bits;
}

// ---------------------------------------------------------------------------
// Fused pred-net + enc_proj: bx<130 -> pred (4 rows each), else enc tile.
// Pred: fp16 weight images, fp32 accumulate.
// ---------------------------------------------------------------------------
__global__ __launch_bounds__(256, 3) void fused_pe(
    const int* __restrict__ targets, const int* __restrict__ tsz,
    const float* __restrict__ emb,
    const unsigned short* __restrict__ W1h, const float* __restrict__ b1,
    const unsigned short* __restrict__ W2h, const float* __restrict__ b2,
    const unsigned short* __restrict__ Wph, const float* __restrict__ bj1,
    float* __restrict__ pproj,
    const float* __restrict__ A,
    const unsigned short* __restrict__ WeF,
    const int* __restrict__ esz, float* __restrict__ eproj)
{
    __shared__ __align__(16) unsigned char smem[24576];
    const int tid = threadIdx.x;

    if (blockIdx.x < 130) {
        // ================= pred part =================
        float (*eS)[256] = (float(*)[256])smem;
        float (*pS)[256] = (float(*)[256])(smem + 4096);
        const int r0 = blockIdx.x * PRROWS;
        const _Float16* __restrict__ W1f = (const _Float16*)W1h;
        const _Float16* __restrict__ W2f = (const _Float16*)W2h;
        const _Float16* __restrict__ Wpf = (const _Float16*)Wph;

        bool anyLive = false;
        #pragma unroll
        for (int i = 0; i < PRROWS; ++i) {
            const int row = r0 + i, b = row / UP1, u = row % UP1;
            anyLive = anyLive || (u <= tsz[b]);
        }
        if (!anyLive) return;

        #pragma unroll
        for (int i = 0; i < PRROWS; ++i) {
            const int row = r0 + i, b = row / UP1, u = row % UP1;
            const int c0 = (u >= 1) ? targets[b * NUT + u - 1] : (VOCAB - 1);
            const int c1 = (u >= 2) ? targets[b * NUT + u - 2] : (VOCAB - 1);
            eS[i][tid] = (tid < EMBD) ? emb[c0 * EMBD + tid]
                                      : emb[c1 * EMBD + (tid - EMBD)];
        }
        __syncthreads();
        {   // layer 1
            float f[PRROWS] = {};
            for (int k = 0; k < 256; k += 4) {
                const float w0 = (float)W1f[(k + 0) * PREDD + tid];
                const float w1 = (float)W1f[(k + 1) * PREDD + tid];
                const float w2 = (float)W1f[(k + 2) * PREDD + tid];
                const float w3 = (float)W1f[(k + 3) * PREDD + tid];
                #pragma unroll
                for (int i = 0; i < PRROWS; ++i) {
                    const float4 e = *(const float4*)&eS[i][k];
                    f[i] = fmaf(e.x, w0, fmaf(e.y, w1, fmaf(e.z, w2, fmaf(e.w, w3, f[i]))));
                }
            }
            const float bb = b1[tid];
            #pragma unroll
            for (int i = 0; i < PRROWS; ++i) pS[i][tid] = frelu(f[i] + bb);
        }
        __syncthreads();
        {   // layer 2 -> eS
            float f[PRROWS] = {};
            for (int k = 0; k < 256; k += 4) {
                const float w0 = (float)W2f[(k + 0) * PREDD + tid];
                const float w1 = (float)W2f[(k + 1) * PREDD + tid];
                const float w2 = (float)W2f[(k + 2) * PREDD + tid];
                const float w3 = (float)W2f[(k + 3) * PREDD + tid];
                #pragma unroll
                for (int i = 0; i < PRROWS; ++i) {
                    const float4 p = *(const float4*)&pS[i][k];
                    f[i] = fmaf(p.x, w0, fmaf(p.y, w1, fmaf(p.z, w2, fmaf(p.w, w3, f[i]))));
                }
            }
            const float bb = b2[tid];
            #pragma unroll
            for (int i = 0; i < PRROWS; ++i) eS[i][tid] = frelu(f[i] + bb);
        }
        __syncthreads();
        #pragma unroll
        for (int h = 0; h < 2; ++h) {   // projection, 512 cols
            const int col = tid + h * 256;
            float g[PRROWS] = {};
            for (int k = 0; k < 256; k += 4) {
                const float w0 = (float)Wpf[(k + 0) * JOIND + col];
                const float w1 = (float)Wpf[(k + 1) * JOIND + col];
                const float w2 = (float)Wpf[(k + 2) * JOIND + col];
                const float w3 = (float)Wpf[(k + 3) * JOIND + col];
                #pragma unroll
                for (int i = 0; i < PRROWS; ++i) {
                    const float4 qv = *(const float4*)&eS[i][k];
                    g[i] = fmaf(qv.x, w0, fmaf(qv.y, w1, fmaf(qv.z, w2, fmaf(qv.w, w3, g[i]))));
                }
            }
            const float bb = bj1[col];
            #pragma unroll
            for (int i = 0; i < PRROWS; ++i)
                pproj[(size_t)(r0 + i) * JOIND + col] = g[i] + bb;
        }
        return;
    }

    // ================= enc part (fp16 2-term, prefetch) =================
    unsigned short* AhS = (unsigned short*)smem;             // 8KB
    unsigned short* AlS = (unsigned short*)(smem + 8192);    // 8KB
    unsigned short* BhS = (unsigned short*)(smem + 16384);   // 8KB

    const int bxe = blockIdx.x - 130;
    const int rTile = bxe >> 2;                   // 0..31
    const int ct = bxe & 3;
    const int b = rTile >> 2;
    const int t0 = (rTile & 3) * 128;
    if (t0 >= esz[b]) return;

    const int q = tid & 7;
    const float* ap[4]; int offA[4];
    #pragma unroll
    for (int p = 0; p < 4; ++p) {
        const int r = p * 32 + (tid >> 3);
        ap[p] = A + (size_t)(rTile * 128 + r) * ENCD + q * 4;
        offA[p] = r * 32 + (((q >> 1) ^ (r & 3)) << 3) + ((q & 1) << 2);
    }
    const size_t wbase = (size_t)ct * 65536;      // f16 units

    const int lane = tid & 63, w = tid >> 6;
    const int wr = w >> 1, wc = w & 1;
    const int l15 = lane & 15, lj = lane >> 4;
    const int sw = lj ^ (l15 & 3);

    f32x4 acc[4][4];
    #pragma unroll
    for (int mt = 0; mt < 4; ++mt)
        #pragma unroll
        for (int nt = 0; nt < 4; ++nt)
            acc[mt][nt] = (f32x4){0.f, 0.f, 0.f, 0.f};

    float4 aReg[4]; uint4 bReg0, bReg1;
    {   // prologue load chunk 0
        #pragma unroll
        for (int p = 0; p < 4; ++p) aReg[p] = *(const float4*)(ap[p]);
        bReg0 = *(const uint4*)&WeF[wbase + (size_t)tid * 8];
        bReg1 = *(const uint4*)&WeF[wbase + (size_t)(tid + 256) * 8];
    }

    for (int c = 0; c < 16; ++c) {
        __syncthreads();
        // STORE staged regs -> LDS
        #pragma unroll
        for (int p = 0; p < 4; ++p) {
            unsigned h0, h1, l0, l1;
            splitf16_2(aReg[p].x, aReg[p].y, h0, l0);
            splitf16_2(aReg[p].z, aReg[p].w, h1, l1);
            *(uint2*)&AhS[offA[p]] = make_uint2(h0, h1);
            *(uint2*)&AlS[offA[p]] = make_uint2(l0, l1);
        }
        *(uint4*)&BhS[tid * 8] = bReg0;
        *(uint4*)&BhS[(tid + 256) * 8] = bReg1;
        __syncthreads();
        if (c < 15) {   // prefetch next chunk
            const int kc = (c + 1) * 32;
            #pragma unroll
            for (int p = 0; p < 4; ++p) aReg[p] = *(const float4*)(ap[p] + kc);
            const size_t g = wbase + ((size_t)(c + 1) << 12);
            bReg0 = *(const uint4*)&WeF[g + (size_t)tid * 8];
            bReg1 = *(const uint4*)&WeF[g + (size_t)(tid + 256) * 8];
        }
        // COMPUTE chunk c
        f16x8 bh[4];
        #pragma unroll
        for (int nt = 0; nt < 4; ++nt) {
            const int n = wc * 64 + nt * 16 + l15;
            bh[nt] = *(const f16x8*)&BhS[n * 32 + (sw << 3)];
        }
        #pragma unroll
        for (int mt = 0; mt < 4; ++mt) {
            const int m = wr * 64 + mt * 16 + l15;
            const int off = m * 32 + (sw << 3);
            const f16x8 ah = *(const f16x8*)&AhS[off];
            const f16x8 al = *(const f16x8*)&AlS[off];
            #pragma unroll
            for (int nt = 0; nt < 4; ++nt) {
                acc[mt][nt] = __builtin_amdgcn_mfma_f32_16x16x32_f16(ah, bh[nt], acc[mt][nt], 0, 0, 0);
                acc[mt][nt] = __builtin_amdgcn_mfma_f32_16x16x32_f16(al, bh[nt], acc[mt][nt], 0, 0, 0);
            }
        }
    }
    #pragma unroll
    for (int mt = 0; mt < 4; ++mt)
        #pragma unroll
        for (int r4 = 0; r4 < 4; ++r4) {
            const int row = wr * 64 + mt * 16 + lj * 4 + r4;
            float* dst = eproj + (size_t)(rTile * 128 + row) * JOIND
                       + ct * 128 + wc * 64 + l15;
            #pragma unroll
            for (int nt = 0; nt < 4; ++nt) dst[nt * 16] = acc[mt][nt][r4];
        }
}

// ---------------------------------------------------------------------------
// Joint: 1-D grid 2304, XCD remap (one batch per XCD).
// Block = 128 rows (16t x 8u) x 128 v; 4 waves, each 32 rows x 128 cols.
// e + p staged once per chunk (f32, XOR-swizzled); h -> single RNE fp16;
// B single fp16 image; bj2 pre-loaded into accumulator (C-in = bias).
// ---------------------------------------------------------------------------
__global__ __launch_bounds__(256, 3) void joint_kernel(
    const float* __restrict__ Eproj, const float* __restrict__ Pproj,
    const unsigned short* __restrict__ WjF,
    const float* __restrict__ bj2,
    const int* __restrict__ esz, const int* __restrict__ tsz,
    float* __restrict__ out)
{
    const int flat = blockIdx.x;                      // 0..2303
    const int logical = (flat & 7) * 288 + (flat >> 3);
    const int b  = logical / 288;
    const int rem = logical - b * 288;
    const int t0 = (rem / 9) * 16;
    const int u0 = (rem % 9) * 8;
    const int tid = threadIdx.x;
    const int es = esz[b], ts = tsz[b];
    const int nu = (UP1 - u0 < 8) ? (UP1 - u0) : 8;   // 8 or 1

    if (t0 >= es || u0 > ts) {   // fully masked -> zero fill
        const float4 z = {0.f, 0.f, 0.f, 0.f};
        const int total = 16 * nu * 32;               // float4 count
        for (int idx = tid; idx < total; idx += 256) {
            const int slot = idx & 31;
            const int rr = idx >> 5;
            const int tt = (nu == 8) ? (rr >> 3) : rr;
            const int uu = (nu == 8) ? (rr & 7) : 0;
            *(float4*)&out[(((size_t)(b * NT + t0 + tt) * UP1 + (u0 + uu)) << 7) + slot * 4] = z;
        }
        return;
    }

    __shared__ __align__(16) unsigned short BhS[128 * 32];  // 8KB fp16
    __shared__ __align__(16) float eS[16 * 32];             // 2KB
    __shared__ __align__(16) float pS[8 * 32];              // 1KB

    // staging assignments
    const int erow = tid >> 3, es8 = tid & 7;               // tid < 128
    const float* egp = Eproj + ((size_t)(b * NT + t0 + (erow & 15))) * JOIND + es8 * 4;
    float* elp = eS + (erow & 15) * 32 + ((es8 ^ (erow & 7)) << 2);
    const int prow = (tid >> 3) & 7, ps8 = tid & 7;         // tid in [128,192)
    int pu = u0 + prow; if (pu > NUT) pu = NUT;
    const float* pgp = Pproj + ((size_t)(b * UP1 + pu)) * JOIND + ps8 * 4;
    float* plp = pS + prow * 32 + ((ps8 ^ (prow & 7)) << 2);

    const int lane = tid & 63, w = tid >> 6;                // wave = 32r x 128c
    const int l15 = lane & 15, lj = lane >> 4;
    const int sw = lj ^ (l15 & 3);
    const int urow = l15 & 7;
    const int po = urow * 32 + (((lj << 1) ^ (urow & 7)) << 2);
    int eo[2];
    #pragma unroll
    for (int mt = 0; mt < 2; ++mt) {
        const int trow = w * 4 + mt * 2 + (l15 >> 3);
        eo[mt] = trow * 32 + (((lj << 1) ^ (trow & 7)) << 2);
    }
    int bo[8];
    #pragma unroll
    for (int nt = 0; nt < 8; ++nt)
        bo[nt] = (nt * 16 + l15) * 32 + (sw << 3);

    // accumulator pre-loaded with bj2 (C-in = bias; masked rows overwrite 0)
    f32x4 acc[2][8];
    #pragma unroll
    for (int nt = 0; nt < 8; ++nt) {
        const float bjv = bj2[nt * 16 + l15];
        acc[0][nt] = (f32x4){bjv, bjv, bjv, bjv};
        acc[1][nt] = (f32x4){bjv, bjv, bjv, bjv};
    }

    float4 aReg; uint4 bReg0, bReg1;
    {   // prologue load chunk 0
        if (tid < 128)       aReg = *(const float4*)egp;
        else if (tid < 192)  aReg = *(const float4*)pgp;
        bReg0 = *(const uint4*)&WjF[(size_t)tid * 8];
        bReg1 = *(const uint4*)&WjF[(size_t)(tid + 256) * 8];
    }

    for (int c = 0; c < 16; ++c) {
        __syncthreads();
        // STORE staged regs -> LDS
        if (tid < 128)      *(float4*)elp = aReg;
        else if (tid < 192) *(float4*)plp = aReg;
        *(uint4*)&BhS[tid * 8] = bReg0;
        *(uint4*)&BhS[(tid + 256) * 8] = bReg1;
        __syncthreads();
        if (c < 15) {   // prefetch next chunk
            const int kc = (c + 1) * 32;
            if (tid < 128)      aReg = *(const float4*)(egp + kc);
            else if (tid < 192) aReg = *(const float4*)(pgp + kc);
            const size_t g = (size_t)(c + 1) << 12;
            bReg0 = *(const uint4*)&WjF[g + (size_t)tid * 8];
            bReg1 = *(const uint4*)&WjF[g + (size_t)(tid + 256) * 8];
        }
        // COMPUTE chunk c — single RNE fp16 A, rows converted once per wave
        f16x8 bh[8];
        #pragma unroll
        for (int nt = 0; nt < 8; ++nt)
            bh[nt] = *(const f16x8*)&BhS[bo[nt]];
        const float4 pf0 = *(const float4*)&pS[po];
        const float4 pf1 = *(const float4*)&pS[po ^ 4];
        #pragma unroll
        for (int mt = 0; mt < 2; ++mt) {
            const float4 ef0 = *(const float4*)&eS[eo[mt]];
            const float4 ef1 = *(const float4*)&eS[eo[mt] ^ 4];
            f16x8 ah;
            ah[0] = (_Float16)frelu(ef0.x + pf0.x);
            ah[1] = (_Float16)frelu(ef0.y + pf0.y);
            ah[2] = (_Float16)frelu(ef0.z + pf0.z);
            ah[3] = (_Float16)frelu(ef0.w + pf0.w);
            ah[4] = (_Float16)frelu(ef1.x + pf1.x);
            ah[5] = (_Float16)frelu(ef1.y + pf1.y);
            ah[6] = (_Float16)frelu(ef1.z + pf1.z);
            ah[7] = (_Float16)frelu(ef1.w + pf1.w);
            #pragma unroll
            for (int nt = 0; nt < 8; ++nt)
                acc[mt][nt] = __builtin_amdgcn_mfma_f32_16x16x32_f16(ah, bh[nt], acc[mt][nt], 0, 0, 0);
        }
    }

    // epilogue: mask, store (D layout: col=lane&15, row=lj*4+reg). bias is in.
    #pragma unroll
    for (int mt = 0; mt < 2; ++mt) {
        #pragma unroll
        for (int r4 = 0; r4 < 4; ++r4) {
            const int row = w * 32 + mt * 16 + lj * 4 + r4;
            const int t = t0 + (row >> 3);
            const int u = u0 + (row & 7);
            if (u >= UP1) continue;                  // u0=64 tiles only
            const bool valid = (t < es) && (u <= ts);
            float* __restrict__ orow =
                out + ((size_t)(b * NT + t) * UP1 + u) * VOCAB + l15;
            #pragma unroll
            for (int nt = 0; nt < 8; ++nt)
                orow[nt * 16] = valid ? acc[mt][nt][r4] : 0.f;
        }
    }
}

// ---------------------------------------------------------------------------
extern "C" void kernel_launch(void* const* d_in, const int* in_sizes, int n_in,
                              void* d_out, int out_size, void* d_ws, size_t ws_size,
                              hipStream_t stream) {
    (void)in_sizes; (void)n_in; (void)out_size; (void)ws_size;
    const float* enc     = (const float*)d_in[0];
    const int*   esz     = (const int*)d_in[1];
    const int*   targets = (const int*)d_in[2];
    const int*   tsz     = (const int*)d_in[3];
    const float* emb     = (const float*)d_in[4];
    const float* W1      = (const float*)d_in[5];
    const float* b1      = (const float*)d_in[6];
    const float* W2      = (const float*)d_in[7];
    const float* b2      = (const float*)d_in[8];
    const float* Wj1     = (const float*)d_in[9];
    const float* bj1     = (const float*)d_in[10];
    const float* Wj2     = (const float*)d_in[11];
    const float* bj2     = (const float*)d_in[12];
    float* out = (float*)d_out;

    // workspace layout
    float* eproj = (float*)d_ws;                                   // 8 MB
    float* pproj = eproj + (size_t)NB * NT * JOIND;                // 1.04 MB
    unsigned short* WjF = (unsigned short*)(pproj + (size_t)NB * UP1 * JOIND);
    unsigned short* WeF = WjF + 65536;                             // 512KB
    unsigned short* W1h = WeF + 262144;                            // 128KB
    unsigned short* W2h = W1h + 65536;                             // 128KB
    unsigned short* Wph = W2h + 65536;                             // 256KB

    prep_weights<<<2304, 256, 0, stream>>>(Wj2, Wj1, W1, W2,
                                           WjF, WeF, W1h, W2h, Wph);
    fused_pe<<<258, 256, 0, stream>>>(targets, tsz, emb, W1h, b1, W2h, b2,
                                      Wph, bj1, pproj,
                                      enc, WeF, esz, eproj);
    joint_kernel<<<2304, 256, 0, stream>>>(eproj, pproj, WjF,
                                           bj2, esz, tsz, out);
}